// Round 5
// baseline (68721.094 us; speedup 1.0000x reference)
//
#include <hip/hip_runtime.h>
#include <stdint.h>

// Decoder_71683004171173: persistent-kernel Tacotron decoder on gfx950.
// R5: LDS-persistent weights. FETCH_SIZE showed 38.4 MB/step = the whole LSTM
// weight set re-streamed from HBM every step (36 MB > 32 MB L2) -> the kernel
// was weight-bandwidth-bound at ~470 GB/s effective. 256 blocks (1/CU) pin all
// big weight matrices in LDS once: S1 blocks own 32 rows of awih[:,0:768]+awhh,
// S3 blocks own 32 rows of dwih[:,0:1024]+dwhh; dwih ctx-part + pw stream from
// (now-quiet) L2. GEMMs read B from swizzled LDS, A via batched bypass loads;
// 8-wave K-quarter split + LDS gates reduction. a1 on all 256 blocks (64-wide
// chunks). Barrier scheme from R4 (relaxed bypass flags).

typedef __attribute__((ext_vector_type(8))) short short8;
typedef __attribute__((ext_vector_type(4))) float floatx4;
typedef unsigned long long u64t;

#define NBLK 256
#define WOFF 131072
#define DYN_LDS 161408

#define MFMA(a, b, c) __builtin_amdgcn_mfma_f32_16x16x32_bf16(a, b, c, 0, 0, 0)

__device__ __forceinline__ float b2f(unsigned short u) {
  union { unsigned int i; float f; } v; v.i = ((unsigned int)u) << 16; return v.f;
}
__device__ __forceinline__ unsigned short f2b(float f) {
  union { float f; unsigned int i; } v; v.f = f;
  unsigned int r = v.i + 0x7FFFu + ((v.i >> 16) & 1u);   // RNE
  return (unsigned short)(r >> 16);
}
__device__ __forceinline__ void stout(void* out, size_t idx, float v, int isbf) {
  if (isbf) ((unsigned short*)out)[idx] = f2b(v);
  else      ((float*)out)[idx] = v;
}
__device__ __forceinline__ float sigm(float x) {
  float xc = fminf(fmaxf(x, -30.f), 30.f);
  return 1.f / (1.f + __expf(-xc));
}
__device__ __forceinline__ float tanh_(float x) {
  float xc = fminf(fmaxf(x, -15.f), 15.f);
  float e = __expf(2.f * xc);
  return (e - 1.f) / (e + 1.f);
}
__device__ __forceinline__ float rdlane_f(float v, int l) {
  return __int_as_float(__builtin_amdgcn_readlane(__float_as_int(v), l));
}

// ---- coherent (cache-bypass) scalar accessors (relaxed agent atomics) ----
__device__ __forceinline__ float ld_f32c(const float* p) {
  union { unsigned int u; float f; } v;
  v.u = __hip_atomic_load((const unsigned int*)p, __ATOMIC_RELAXED, __HIP_MEMORY_SCOPE_AGENT);
  return v.f;
}
__device__ __forceinline__ void st_f32c(float* p, float f) {
  union { float f; unsigned int u; } v; v.f = f;
  __hip_atomic_store((unsigned int*)p, v.u, __ATOMIC_RELAXED, __HIP_MEMORY_SCOPE_AGENT);
}
__device__ __forceinline__ void st_u32c(unsigned short* p, unsigned int u) {
  __hip_atomic_store((unsigned int*)p, u, __ATOMIC_RELAXED, __HIP_MEMORY_SCOPE_AGENT);
}
__device__ __forceinline__ u64t ld_u64c(const void* p) {
  return __hip_atomic_load((const u64t*)p, __ATOMIC_RELAXED, __HIP_MEMORY_SCOPE_AGENT);
}

// ---- pipelined 16B loads via inline asm (issue now, wait explicitly) ----
__device__ __forceinline__ short8 ld16_cb(const unsigned short* p) {   // L1+L2 bypass
  short8 r;
  asm volatile("global_load_dwordx4 %0, %1, off sc0 sc1" : "=v"(r) : "v"(p));
  return r;
}
__device__ __forceinline__ short8 ld16_nc(const unsigned short* p) {   // normal cached
  short8 r;
  asm volatile("global_load_dwordx4 %0, %1, off" : "=v"(r) : "v"(p));
  return r;
}
__device__ __forceinline__ void vmwait0() {
  asm volatile("s_waitcnt vmcnt(0)" ::: "memory");
  __builtin_amdgcn_sched_barrier(0);   // rule #18
}

struct Params {
  const unsigned short *memb;
  const unsigned short *awih, *awhh;
  const unsigned short *cw, *ldw, *vw, *vb;
  const unsigned short *dwih, *dwhh, *dbih, *dbhh;
  const unsigned short *pw, *pb, *gw, *gb;
  const float *pmemT, *gemo, *qwf, *ldwf;
  float *ahf, *aw, *cum, *eng;
  unsigned short *xpre;
  unsigned short *ahb, *dhb, *ctxb;
  void *out;
  unsigned int *flags;
  const unsigned int *dflag;
};

// Work-region structs (all live at lds + WOFF, time-disjoint):
struct A1W {                 // 30336 B
  float cwT0[992], cwT1[992], vvp[128];
  float awh0[96], awh1[96];
  float ahs[1056];           // [4][264]
  float pqp[512];
  float pq[128];
  float loc[64 * 48];
  float epart[512];
};
struct A2W { float w[512]; float red[8]; float red2[8]; float cr[4096]; };  // 18496 B
// gates: float[4][32][33] = 16896 B ; proj partials: float[8][32][17] = 17408 B

// ---- grid barrier: relaxed bypass store + relaxed bypass polls (R4, proven) ----
__device__ __forceinline__ void gbar(unsigned int* flags, unsigned int gen, int bid, int tid) {
  __syncthreads();
  if (tid == 0)
    __hip_atomic_store(&flags[bid], gen, __ATOMIC_RELAXED, __HIP_MEMORY_SCOPE_AGENT);
  if (tid < NBLK) {
    while (__hip_atomic_load(&flags[tid], __ATOMIC_RELAXED, __HIP_MEMORY_SCOPE_AGENT) < gen)
      __builtin_amdgcn_s_sleep(1);
  }
  __syncthreads();
}

// ---- attention LSTM step ts; block g in [0,128) owns j in [g*8, g*8+8) ----
// rows r = c*1024 + g*8 + jj ; LDS B: wih [32n][96u] (K=768 runtime part), whh [32n][128u]
__device__ __forceinline__ void s1_block(const Params& P, char* lds, int ts, int g, int tid, float& ac_reg) {
  const unsigned short* wih = (const unsigned short*)lds;
  const unsigned short* whh = (const unsigned short*)(lds + 49152);
  float* gt = (float*)(lds + WOFF);    // [4][32][33]
  const int w = tid >> 6, lane = tid & 63;
  const int h = w >> 2, kq = w & 3;
  const int kg = lane >> 4, nn = lane & 15, mm = lane & 15;
  const int pa = (ts + 1) & 1;
  floatx4 acc00 = {0.f,0.f,0.f,0.f}, acc01 = {0.f,0.f,0.f,0.f};
  floatx4 acc10 = {0.f,0.f,0.f,0.f}, acc11 = {0.f,0.f,0.f,0.f};
  const int sw = nn & 7;
  if (h) {   // whh over ah(ts-1), K = 1024, quarter = 256
    const unsigned short* ast = P.ahb + pa * (32 * 1024);
    const int kb0 = kq * 256;
    #pragma unroll
    for (int hf = 0; hf < 2; ++hf) {
      short8 a0[4], a1r[4];
      #pragma unroll
      for (int i = 0; i < 4; ++i) {
        const int k = kb0 + hf * 128 + i * 32 + kg * 8;
        a0[i]  = ld16_cb(ast + mm * 1024 + k);
        a1r[i] = ld16_cb(ast + (mm + 16) * 1024 + k);
      }
      vmwait0();
      #pragma unroll
      for (int i = 0; i < 4; ++i) {
        const int c = ((kb0 + hf * 128 + i * 32) >> 3) + kg;
        short8 b0 = *(const short8*)(whh + ((nn * 128 + (c ^ sw)) << 3));
        short8 b1 = *(const short8*)(whh + (((nn + 16) * 128 + (c ^ sw)) << 3));
        acc00 = MFMA(a0[i], b0, acc00);
        acc01 = MFMA(a0[i], b1, acc01);
        acc10 = MFMA(a1r[i], b0, acc10);
        acc11 = MFMA(a1r[i], b1, acc11);
      }
    }
  } else {   // wih over [xpre 256 | ctx 512], virtual K = 768, quarter = 192
    const unsigned short* xp = P.xpre + (size_t)ts * 32 * 256;
    const unsigned short* cx = P.ctxb + pa * (32 * 512);
    const int kb0 = kq * 192;
    #pragma unroll
    for (int hf = 0; hf < 2; ++hf) {
      short8 a0[3], a1r[3];
      #pragma unroll
      for (int i = 0; i < 3; ++i) {
        const int vk = kb0 + hf * 96 + i * 32 + kg * 8;
        if (vk < 256) {
          a0[i]  = *(const short8*)(xp + mm * 256 + vk);
          a1r[i] = *(const short8*)(xp + (mm + 16) * 256 + vk);
        } else {
          a0[i]  = ld16_cb(cx + mm * 512 + vk - 256);
          a1r[i] = ld16_cb(cx + (mm + 16) * 512 + vk - 256);
        }
      }
      vmwait0();
      #pragma unroll
      for (int i = 0; i < 3; ++i) {
        const int c = ((kb0 + hf * 96 + i * 32) >> 3) + kg;
        short8 b0 = *(const short8*)(wih + ((nn * 96 + (c ^ sw)) << 3));
        short8 b1 = *(const short8*)(wih + (((nn + 16) * 96 + (c ^ sw)) << 3));
        acc00 = MFMA(a0[i], b0, acc00);
        acc01 = MFMA(a0[i], b1, acc01);
        acc10 = MFMA(a1r[i], b0, acc10);
        acc11 = MFMA(a1r[i], b1, acc11);
      }
    }
  }
  const int rb = kg * 4;
  if (!h) {
    #pragma unroll
    for (int v = 0; v < 4; ++v) {
      gt[(kq * 32 + rb + v) * 33 + nn]           = acc00[v];
      gt[(kq * 32 + rb + v) * 33 + nn + 16]      = acc01[v];
      gt[(kq * 32 + rb + v + 16) * 33 + nn]      = acc10[v];
      gt[(kq * 32 + rb + v + 16) * 33 + nn + 16] = acc11[v];
    }
  }
  __syncthreads();
  if (h) {
    #pragma unroll
    for (int v = 0; v < 4; ++v) {
      gt[(kq * 32 + rb + v) * 33 + nn]           += acc00[v];
      gt[(kq * 32 + rb + v) * 33 + nn + 16]      += acc01[v];
      gt[(kq * 32 + rb + v + 16) * 33 + nn]      += acc10[v];
      gt[(kq * 32 + rb + v + 16) * 33 + nn + 16] += acc11[v];
    }
  }
  __syncthreads();
  if (tid < 256) {
    const int b = tid >> 3, jl = tid & 7, j = g * 8 + jl;
    const float* gm = P.gemo + b * 4096 + j;
    float gs[4];
    #pragma unroll
    for (int c4 = 0; c4 < 4; ++c4) {
      float s = 0.f;
      #pragma unroll
      for (int q2 = 0; q2 < 4; ++q2) s += gt[(q2 * 32 + b) * 33 + c4 * 8 + jl];
      gs[c4] = s;
    }
    float gi = gs[0] + gm[0], gf = gs[1] + gm[1024], gc = gs[2] + gm[2048], go = gs[3] + gm[3072];
    float cn = sigm(gf) * ac_reg + sigm(gi) * tanh_(gc);
    float hn = sigm(go) * tanh_(cn);
    ac_reg = cn;
    st_f32c(&P.ahf[b * 1024 + j], hn);
    unsigned int hb = f2b(hn);
    unsigned int nb = (unsigned int)__shfl_down((int)hb, 1) & 0xFFFFu;
    if (!(jl & 1))
      st_u32c(P.ahb + (ts & 1) * (32 * 1024) + b * 1024 + j, hb | (nb << 16));
  }
}

// ---- decoder LSTM step ts; block g in [0,128) owns j in [g*8, g*8+8) ----
// LDS B: dwih-ah [32n][128u], dwhh [32n][128u]; dwih-ctx streamed from L2.
__device__ __forceinline__ void s3_block(const Params& P, char* lds, int ts, int g, int tid, float& dc_reg) {
  const unsigned short* wia = (const unsigned short*)lds;
  const unsigned short* whh = (const unsigned short*)(lds + 65536);
  float* gt = (float*)(lds + WOFF);
  const int w = tid >> 6, lane = tid & 63;
  const int h = w >> 2, kq = w & 3;
  const int kg = lane >> 4, nn = lane & 15, mm = lane & 15;
  const int pa = ts & 1, pd = (ts + 1) & 1;
  floatx4 acc00 = {0.f,0.f,0.f,0.f}, acc01 = {0.f,0.f,0.f,0.f};
  floatx4 acc10 = {0.f,0.f,0.f,0.f}, acc11 = {0.f,0.f,0.f,0.f};
  const int sw = nn & 7;
  if (h) {   // dwhh over dh(ts-1), K = 1024
    const unsigned short* ast = P.dhb + pd * (32 * 1024);
    const int kb0 = kq * 256;
    #pragma unroll
    for (int hf = 0; hf < 2; ++hf) {
      short8 a0[4], a1r[4];
      #pragma unroll
      for (int i = 0; i < 4; ++i) {
        const int k = kb0 + hf * 128 + i * 32 + kg * 8;
        a0[i]  = ld16_cb(ast + mm * 1024 + k);
        a1r[i] = ld16_cb(ast + (mm + 16) * 1024 + k);
      }
      vmwait0();
      #pragma unroll
      for (int i = 0; i < 4; ++i) {
        const int c = ((kb0 + hf * 128 + i * 32) >> 3) + kg;
        short8 b0 = *(const short8*)(whh + ((nn * 128 + (c ^ sw)) << 3));
        short8 b1 = *(const short8*)(whh + (((nn + 16) * 128 + (c ^ sw)) << 3));
        acc00 = MFMA(a0[i], b0, acc00);
        acc01 = MFMA(a0[i], b1, acc01);
        acc10 = MFMA(a1r[i], b0, acc10);
        acc11 = MFMA(a1r[i], b1, acc11);
      }
    }
  } else {   // dwih over [ah 1024 | ctx 512], virtual K = 1536, quarter = 384
    const unsigned short* ah = P.ahb + pa * (32 * 1024);
    const unsigned short* cx = P.ctxb + pa * (32 * 512);
    const int rz0 = (nn >> 3) * 1024 + g * 8 + (nn & 7);   // row of n-tile0; n-tile1 = +2048
    const int kb0 = kq * 384;
    #pragma unroll
    for (int bt = 0; bt < 3; ++bt) {
      const int base = kb0 + bt * 128;
      if (base < 1024) {   // pure-ah batch (batches never straddle 1024)
        short8 a0[4], a1r[4];
        #pragma unroll
        for (int i = 0; i < 4; ++i) {
          const int k = base + i * 32 + kg * 8;
          a0[i]  = ld16_cb(ah + mm * 1024 + k);
          a1r[i] = ld16_cb(ah + (mm + 16) * 1024 + k);
        }
        vmwait0();
        #pragma unroll
        for (int i = 0; i < 4; ++i) {
          const int c = ((base + i * 32) >> 3) + kg;
          short8 b0 = *(const short8*)(wia + ((nn * 128 + (c ^ sw)) << 3));
          short8 b1 = *(const short8*)(wia + (((nn + 16) * 128 + (c ^ sw)) << 3));
          acc00 = MFMA(a0[i], b0, acc00);
          acc01 = MFMA(a0[i], b1, acc01);
          acc10 = MFMA(a1r[i], b0, acc10);
          acc11 = MFMA(a1r[i], b1, acc11);
        }
      } else {             // pure-ctx batch: A bypass, B streamed from L2
        short8 a0[4], a1r[4], b0g[4], b1g[4];
        #pragma unroll
        for (int i = 0; i < 4; ++i) {
          const int k = base + i * 32 + kg * 8;
          a0[i]  = ld16_cb(cx + mm * 512 + k - 1024);
          a1r[i] = ld16_cb(cx + (mm + 16) * 512 + k - 1024);
          b0g[i] = ld16_nc(P.dwih + (size_t)rz0 * 1536 + k);
          b1g[i] = ld16_nc(P.dwih + (size_t)(rz0 + 2048) * 1536 + k);
        }
        vmwait0();
        #pragma unroll
        for (int i = 0; i < 4; ++i) {
          acc00 = MFMA(a0[i], b0g[i], acc00);
          acc01 = MFMA(a0[i], b1g[i], acc01);
          acc10 = MFMA(a1r[i], b0g[i], acc10);
          acc11 = MFMA(a1r[i], b1g[i], acc11);
        }
      }
    }
  }
  const int rb = kg * 4;
  if (!h) {
    #pragma unroll
    for (int v = 0; v < 4; ++v) {
      gt[(kq * 32 + rb + v) * 33 + nn]           = acc00[v];
      gt[(kq * 32 + rb + v) * 33 + nn + 16]      = acc01[v];
      gt[(kq * 32 + rb + v + 16) * 33 + nn]      = acc10[v];
      gt[(kq * 32 + rb + v + 16) * 33 + nn + 16] = acc11[v];
    }
  }
  __syncthreads();
  if (h) {
    #pragma unroll
    for (int v = 0; v < 4; ++v) {
      gt[(kq * 32 + rb + v) * 33 + nn]           += acc00[v];
      gt[(kq * 32 + rb + v) * 33 + nn + 16]      += acc01[v];
      gt[(kq * 32 + rb + v + 16) * 33 + nn]      += acc10[v];
      gt[(kq * 32 + rb + v + 16) * 33 + nn + 16] += acc11[v];
    }
  }
  __syncthreads();
  if (tid < 256) {
    const int b = tid >> 3, jl = tid & 7, j = g * 8 + jl;
    float gs[4];
    #pragma unroll
    for (int c4 = 0; c4 < 4; ++c4) {
      float s = 0.f;
      #pragma unroll
      for (int q2 = 0; q2 < 4; ++q2) s += gt[(q2 * 32 + b) * 33 + c4 * 8 + jl];
      gs[c4] = s;
    }
    float gi = gs[0] + b2f(P.dbih[j])        + b2f(P.dbhh[j]);
    float gf = gs[1] + b2f(P.dbih[1024 + j]) + b2f(P.dbhh[1024 + j]);
    float gc = gs[2] + b2f(P.dbih[2048 + j]) + b2f(P.dbhh[2048 + j]);
    float go = gs[3] + b2f(P.dbih[3072 + j]) + b2f(P.dbhh[3072 + j]);
    float cn = sigm(gf) * dc_reg + sigm(gi) * tanh_(gc);
    float hn = sigm(go) * tanh_(cn);
    dc_reg = cn;
    unsigned int hb = f2b(hn);
    unsigned int nb = (unsigned int)__shfl_down((int)hb, 1) & 0xFFFFu;
    if (!(jl & 1))
      st_u32c(P.dhb + (ts & 1) * (32 * 1024) + b * 1024 + j, hb | (nb << 16));
  }
}

// ---- mel + gate projection for step tp; blocks 128..133 (p=0..5), 16 rows each ----
__device__ __forceinline__ void proj_block(const Params& P, char* lds, int tp, int p, int tid) {
  float* pp = (float*)(lds + WOFF);   // [8][32][17]
  const int w = tid >> 6, lane = tid & 63;
  const int kg = lane >> 4, nn = lane & 15, mm = lane & 15;
  const int pd = tp & 1;
  const int r0 = p * 16 + nn;
  const unsigned short* brow = (r0 < 80) ? (P.pw + (size_t)r0 * 1536) : P.gw;
  const unsigned short* dh = P.dhb + pd * (32 * 1024);
  const unsigned short* cx = P.ctxb + pd * (32 * 512);
  floatx4 acc0 = {0.f,0.f,0.f,0.f}, acc1 = {0.f,0.f,0.f,0.f};
  const int kb0 = w * 192;
  #pragma unroll
  for (int bt = 0; bt < 2; ++bt) {
    short8 a0[3], a1r[3], bg[3];
    #pragma unroll
    for (int i = 0; i < 3; ++i) {
      const int vk = kb0 + bt * 96 + i * 32 + kg * 8;
      if (vk < 1024) {
        a0[i]  = ld16_cb(dh + mm * 1024 + vk);
        a1r[i] = ld16_cb(dh + (mm + 16) * 1024 + vk);
      } else {
        a0[i]  = ld16_cb(cx + mm * 512 + vk - 1024);
        a1r[i] = ld16_cb(cx + (mm + 16) * 512 + vk - 1024);
      }
      bg[i] = ld16_nc(brow + vk);
    }
    vmwait0();
    #pragma unroll
    for (int i = 0; i < 3; ++i) {
      acc0 = MFMA(a0[i], bg[i], acc0);
      acc1 = MFMA(a1r[i], bg[i], acc1);
    }
  }
  const int rb = kg * 4;
  #pragma unroll
  for (int v = 0; v < 4; ++v) {
    pp[(w * 32 + rb + v) * 17 + nn]      = acc0[v];
    pp[(w * 32 + rb + v + 16) * 17 + nn] = acc1[v];
  }
  __syncthreads();
  {
    const int isbf = (int)*P.dflag;
    const int b = tid >> 4, nl = tid & 15, r = p * 16 + nl;
    if (r <= 80) {
      float s = 0.f;
      #pragma unroll
      for (int q2 = 0; q2 < 8; ++q2) s += pp[(q2 * 32 + b) * 17 + nl];
      if (r < 80) {
        s += b2f(P.pb[r]);
        stout(P.out, ((size_t)b * 80 + r) * 800 + tp, s, isbf);
      } else {
        s += b2f(P.gb[0]);
        stout(P.out, 2048000u + (size_t)b * 800 + tp, s, isbf);
      }
    }
  }
}

// ---- energies for step t: all 256 blocks; block = (b = bid>>3, 64-wide chunk) ----
__device__ __forceinline__ void a1_block(const Params& P, char* lds, const float* ldwR,
                                         int t, int bid, int tid) {
  A1W& q = *(A1W*)(lds + WOFF);
  const int b = bid >> 3, T0 = (bid & 7) * 64;
  for (int i = tid; i < 992; i += 512) {
    const int k = i >> 5, f = i & 31;
    q.cwT0[i] = b2f(P.cw[f * 62 + k]);
    q.cwT1[i] = b2f(P.cw[f * 62 + 31 + k]);
  }
  {
    union { u64t qq; float f[2]; } u;
    u.qq = ld_u64c(P.ahf + b * 1024 + tid * 2);
    const int v = tid * 2, qq = v >> 8, k = v & 255;
    q.ahs[qq * 264 + k]     = u.f[0];
    q.ahs[qq * 264 + k + 1] = u.f[1];
  }
  if (tid < 96) {
    const int gidx = T0 - 15 + tid;
    q.awh0[tid] = (tid < 94 && gidx >= 0 && gidx < 512) ? ld_f32c(P.aw + b * 512 + gidx) : 0.f;
  } else if (tid >= 128 && tid < 224) {
    const int i = tid - 128, gidx = T0 - 15 + i;
    q.awh1[i] = (i < 94 && gidx >= 0 && gidx < 512) ? ld_f32c(P.cum + b * 512 + gidx) : 0.f;
  } else if (tid >= 256 && tid < 384) {
    q.vvp[tid - 256] = b2f(P.vw[tid - 256]);
  }
  __syncthreads();
  { // pq partials: thread = (a, quarter-of-K)
    const int a = tid >> 2, qq = tid & 3;
    const float* qr = P.qwf + (size_t)a * 1024 + qq * 256;
    const float* al = &q.ahs[qq * 264];
    float s = 0.f;
    #pragma unroll 8
    for (int k = 0; k < 256; k += 4) {
      floatx4 w4 = *(const floatx4*)(qr + k);
      floatx4 a4 = *(const floatx4*)(al + k);
      s += w4[0]*a4[0] + w4[1]*a4[1] + w4[2]*a4[2] + w4[3]*a4[3];
    }
    q.pqp[tid] = s;
  }
  { // location conv: thread = (f, quad of 4 contiguous tl); windows in registers
    const int f = tid & 31, tl0 = (tid >> 5) * 4;
    float a4[4] = {0.f,0.f,0.f,0.f};
    #pragma unroll
    for (int kb = 0; kb < 4; ++kb) {
      const int kbase = kb * 8;
      floatx4 W0[3], W1[3];
      #pragma unroll
      for (int x = 0; x < 3; ++x) {
        W0[x] = *(const floatx4*)&q.awh0[tl0 + kbase + x * 4];
        W1[x] = *(const floatx4*)&q.awh1[tl0 + kbase + x * 4];
      }
      #pragma unroll
      for (int kk = 0; kk < 8; ++kk) {
        if (kbase + kk > 30) break;
        const float c0 = q.cwT0[(kbase + kk) * 32 + f];
        const float c1 = q.cwT1[(kbase + kk) * 32 + f];
        #pragma unroll
        for (int i = 0; i < 4; ++i) {
          const int x = kk + i;
          a4[i] += W0[x >> 2][x & 3] * c0 + W1[x >> 2][x & 3] * c1;
        }
      }
    }
    #pragma unroll
    for (int i = 0; i < 4; ++i) q.loc[(tl0 + i) * 48 + f] = a4[i];
  }
  __syncthreads();
  if (tid < 128) {
    const float* pp = &q.pqp[tid * 4];
    q.pq[tid] = pp[0] + pp[1] + pp[2] + pp[3];
  }
  __syncthreads();
  { // energies: wave aq owns 16 a; lane = tl; ldw via readlane (0 LDS)
    const int aq = tid >> 6, tl = tid & 63;
    floatx4 lr[8];
    #pragma unroll
    for (int j = 0; j < 8; ++j) lr[j] = *(const floatx4*)&q.loc[tl * 48 + j * 4];
    const float* pmr = P.pmemT + ((size_t)b * 128 + aq * 16) * 512 + T0 + tl;
    float part = 0.f;
    #pragma unroll
    for (int ii = 0; ii < 16; ++ii) {
      const int a = aq * 16 + ii;
      float s = q.pq[a] + pmr[(size_t)ii * 512];
      #pragma unroll
      for (int cc = 0; cc < 4; ++cc) {
        #pragma unroll
        for (int j = 0; j < 8; ++j) {
          const float wv_ = rdlane_f(ldwR[j], ii * 4 + cc);
          const int f = cc * 8 + j;
          s += lr[f >> 2][f & 3] * wv_;
        }
      }
      part += q.vvp[a] * tanh_(s);
    }
    q.epart[aq * 64 + tl] = part;
  }
  __syncthreads();
  if (tid < 64) {
    float e = b2f(P.vb[0]);
    #pragma unroll
    for (int j = 0; j < 8; ++j) e += q.epart[j * 64 + tid];
    st_f32c(P.eng + b * 512 + T0 + tid, e);
  }
}

// ---- softmax + context for step t: blocks 0..31 ----
__device__ __forceinline__ void a2_block(const Params& P, char* lds, int t, int b, int tid, float& cum_reg) {
  A2W& s2 = *(A2W*)(lds + WOFF);
  const int lane = tid & 63, wv = tid >> 6;
  const int isbf = (int)*P.dflag;
  float e = ld_f32c(P.eng + b * 512 + tid);
  float m = e;
  #pragma unroll
  for (int off = 32; off; off >>= 1) m = fmaxf(m, __shfl_xor(m, off));
  if (lane == 0) s2.red[wv] = m;
  __syncthreads();
  float M = s2.red[0];
  #pragma unroll
  for (int i = 1; i < 8; ++i) M = fmaxf(M, s2.red[i]);
  float p = __expf(e - M);
  float s = p;
  #pragma unroll
  for (int off = 32; off; off >>= 1) s += __shfl_xor(s, off);
  if (lane == 0) s2.red2[wv] = s;
  __syncthreads();
  float S = s2.red2[0];
  #pragma unroll
  for (int i = 1; i < 8; ++i) S += s2.red2[i];
  float wgt = p / S * (1.f / (1.f + 1e-8f));
  st_f32c(P.aw + b * 512 + tid, wgt);
  cum_reg += wgt;
  st_f32c(P.cum + b * 512 + tid, cum_reg);
  stout(P.out, 2073600u + ((size_t)b * 800 + t) * 512 + tid, wgt, isbf);
  s2.w[tid] = wgt;
  __syncthreads();
  {
    const int eg = tid & 63, tc = tid >> 6;
    const unsigned short* mp = P.memb + (size_t)b * 262144 + (size_t)tc * 64 * 512 + eg * 8;
    float acc[8] = {0.f,0.f,0.f,0.f,0.f,0.f,0.f,0.f};
    #pragma unroll 8
    for (int tau = 0; tau < 64; ++tau) {
      short8 mv = *(const short8*)(mp + (size_t)tau * 512);
      float wv_ = s2.w[tc * 64 + tau];
      #pragma unroll
      for (int j = 0; j < 8; ++j) acc[j] += wv_ * b2f((unsigned short)mv[j]);
    }
    floatx4 c03 = {acc[0], acc[1], acc[2], acc[3]};
    floatx4 c47 = {acc[4], acc[5], acc[6], acc[7]};
    *(floatx4*)&s2.cr[tc * 512 + eg * 8]     = c03;
    *(floatx4*)&s2.cr[tc * 512 + eg * 8 + 4] = c47;
  }
  __syncthreads();
  {
    float cx = 0.f;
    #pragma unroll
    for (int j = 0; j < 8; ++j) cx += s2.cr[j * 512 + tid];
    unsigned int cb = f2b(cx);
    unsigned int nb = (unsigned int)__shfl_down((int)cb, 1) & 0xFFFFu;
    if (!(tid & 1))
      st_u32c(P.ctxb + (t & 1) * (32 * 512) + b * 512 + tid, cb | (nb << 16));
  }
}

__global__ __launch_bounds__(512, 2) void persist_k(Params P) {
  extern __shared__ char lds[];
  const int tid = threadIdx.x, bid = blockIdx.x;
  // ---- persistent weight fill (once) ----
  if (bid < 128) {
    const int g = bid;
    unsigned short* wih = (unsigned short*)lds;
    unsigned short* whh = (unsigned short*)(lds + 49152);
    for (int u = tid; u < 32 * 96; u += 512) {
      const int n = u / 96, c = u % 96;
      const int row = (n >> 3) * 1024 + g * 8 + (n & 7);
      *(short8*)(wih + ((n * 96 + (c ^ (n & 7))) << 3)) =
          *(const short8*)(P.awih + (size_t)row * 1024 + c * 8);
    }
    for (int u = tid; u < 32 * 128; u += 512) {
      const int n = u >> 7, c = u & 127;
      const int row = (n >> 3) * 1024 + g * 8 + (n & 7);
      *(short8*)(whh + ((n * 128 + (c ^ (n & 7))) << 3)) =
          *(const short8*)(P.awhh + (size_t)row * 1024 + c * 8);
    }
  } else {
    const int g = bid - 128;
    unsigned short* wia = (unsigned short*)lds;
    unsigned short* whh = (unsigned short*)(lds + 65536);
    for (int u = tid; u < 32 * 128; u += 512) {
      const int n = u >> 7, c = u & 127;
      const int row = (n >> 3) * 1024 + g * 8 + (n & 7);
      *(short8*)(wia + ((n * 128 + (c ^ (n & 7))) << 3)) =
          *(const short8*)(P.dwih + (size_t)row * 1536 + c * 8);
      *(short8*)(whh + ((n * 128 + (c ^ (n & 7))) << 3)) =
          *(const short8*)(P.dwhh + (size_t)row * 1024 + c * 8);
    }
  }
  float ldwR[8];
  {
    const int a = (tid >> 6) * 16 + ((tid & 63) >> 2);
    const int cc = tid & 3;
    #pragma unroll
    for (int j = 0; j < 8; ++j) ldwR[j] = P.ldwf[a * 32 + cc * 8 + j];
  }
  __syncthreads();
  float ac_reg = 0.f, dc_reg = 0.f, cum_reg = 0.f;
  unsigned int gen = 0;
  if (bid < 128) s1_block(P, lds, 0, bid, tid, ac_reg);
  gbar(P.flags, ++gen, bid, tid);
  for (int t = 0; t < 800; ++t) {
    a1_block(P, lds, ldwR, t, bid, tid);
    gbar(P.flags, ++gen, bid, tid);
    if (bid < 32) a2_block(P, lds, t, bid, tid, cum_reg);
    else if (bid >= 128 && t >= 1) s3_block(P, lds, t - 1, bid - 128, tid, dc_reg);
    gbar(P.flags, ++gen, bid, tid);
    if (bid < 128) { if (t < 799) s1_block(P, lds, t + 1, bid, tid, ac_reg); }
    else if (bid < 134 && t >= 1) proj_block(P, lds, t - 1, bid - 128, tid);
    gbar(P.flags, ++gen, bid, tid);
  }
  if (bid >= 128) s3_block(P, lds, 799, bid - 128, tid, dc_reg);
  gbar(P.flags, ++gen, bid, tid);
  if (bid >= 128 && bid < 134) proj_block(P, lds, 799, bid - 128, tid);
}

// ---------------- dtype detect + canonicalize ----------------
__global__ void detect_k(const unsigned short* vb_raw, unsigned int* dflag) {
  if (threadIdx.x == 0 && blockIdx.x == 0)
    *dflag = (vb_raw[0] == 0xBF80u) ? 1u : 0u;
}

struct CvtJobs {
  const void* src[28];
  unsigned short* dst[28];
  int n[28];
  int cnt;
  const unsigned int* dflag;
};

__global__ void cvt_k(CvtJobs J) {
  const int isbf = (int)*J.dflag;
  const int gid = blockIdx.x * 256 + threadIdx.x, stride = gridDim.x * 256;
  for (int tj = 0; tj < J.cnt; ++tj) {
    const int n = J.n[tj];
    unsigned short* d = J.dst[tj];
    if (isbf) {
      const unsigned short* s = (const unsigned short*)J.src[tj];
      for (int i = gid; i < n; i += stride) d[i] = s[i];
    } else {
      const float* s = (const float*)J.src[tj];
      for (int i = gid; i < n; i += stride) d[i] = f2b(s[i]);
    }
  }
}

__global__ void qwf_k(const unsigned short* qw, float* qwf,
                      const unsigned short* ldw, float* ldwf) {
  const int i = blockIdx.x * 256 + threadIdx.x;   // 131072 = 128 x 1024
  qwf[i] = b2f(qw[i]);
  if (i < 4096) ldwf[i] = b2f(ldw[i]);
}

// ---------------- precompute kernels ----------------
__global__ void prenet_k(const void* dec, const unsigned int* dflag,
                         const unsigned short* w1, const unsigned short* b1,
                         const unsigned short* w2, const unsigned short* b2, unsigned short* xpre) {
  const int t = blockIdx.x, tid = threadIdx.x;
  const int isbf = (int)*dflag;
  __shared__ float sin_[32 * 80];
  __shared__ float h1[32 * 256];
  for (int i = tid; i < 2560; i += 256) {
    int b = i / 80, m = i % 80;
    size_t idx = ((size_t)b * 80 + m) * 800 + t - 1;
    float v;
    if (t == 0) v = -4.5f;
    else if (isbf) v = b2f(((const unsigned short*)dec)[idx]);
    else v = ((const float*)dec)[idx];
    sin_[i] = v;
  }
  __syncthreads();
  for (int u = tid; u < 8192; u += 256) {
    int b = u >> 8, o = u & 255;
    float s = b2f(b1[o]);
    const unsigned short* wr = w1 + o * 80;
    const float* sr = &sin_[b * 80];
    for (int k = 0; k < 80; ++k) s += b2f(wr[k]) * sr[k];
    h1[u] = fmaxf(s, 0.f);
  }
  __syncthreads();
  for (int u = tid; u < 8192; u += 256) {
    int b = u >> 8, o = u & 255;
    float s = b2f(b2[o]);
    const unsigned short* wr = w2 + o * 256;
    const float* hr = &h1[b * 256];
    for (int k = 0; k < 256; ++k) s += b2f(wr[k]) * hr[k];
    xpre[(size_t)(t * 32 + b) * 256 + o] = f2b(fmaxf(s, 0.f));
  }
}

__global__ void gemo_k(const unsigned short* emo, const unsigned short* wih,
                       const unsigned short* bih, const unsigned short* bhh, float* gemo) {
  const int gid = blockIdx.x * 256 + threadIdx.x;
  const int r = gid >> 5, b = gid & 31;
  float s = b2f(bih[r]) + b2f(bhh[r]);
  const unsigned short* wr = wih + (size_t)r * 1024 + 768;
  const unsigned short* er = emo + b * 256;
  for (int k = 0; k < 256; ++k) s += b2f(er[k]) * b2f(wr[k]);
  gemo[b * 4096 + r] = s;
}

__global__ void pmem_k(const void* mem, const unsigned int* dflag, const unsigned short* mw,
                       const unsigned short* mb, float* pmemT) {
  const int b = blockIdx.x >> 5, tq = blockIdx.x & 31, tid = threadIdx.x;
  const int isbf = (int)*dflag;
  __shared__ float mt[16 * 512];
  for (int i = tid; i < 8192; i += 256) {
    size_t idx = (size_t)(b * 512 + tq * 16) * 512 + i;
    mt[i] = isbf ? b2f(((const unsigned short*)mem)[idx]) : ((const float*)mem)[idx];
  }
  __syncthreads();
  for (int u = tid; u < 2048; u += 256) {
    int tl = u >> 7, a = u & 127;
    float s = b2f(mb[a]);
    const unsigned short* wr = mw + a * 512;
    const float* mr = &mt[tl * 512];
    for (int k = 0; k < 512; ++k) s += b2f(wr[k]) * mr[k];
    pmemT[((size_t)b * 128 + a) * 512 + tq * 16 + tl] = s;   // [b][a][t]
  }
}

__global__ void init_k(unsigned short* ahb, unsigned short* dhb, unsigned short* ctxb,
                       float* ahf, float* aw, float* cum, unsigned int* flags) {
  const int gid = blockIdx.x * 256 + threadIdx.x;
  const int n = gridDim.x * 256;
  for (int i = gid; i < 65536; i += n) { ahb[i] = 0; dhb[i] = 0; }
  for (int i = gid; i < 32768; i += n) { ctxb[i] = 0; ahf[i] = 0.f; }
  for (int i = gid; i < 16384; i += n) {
    int tt = i & 511;
    aw[i] = (tt < 5) ? 0.2f : 0.f;
    cum[i] = 0.f;
  }
  for (int i = gid; i < 256; i += n) flags[i] = 0;
}

extern "C" void kernel_launch(void* const* d_in, const int* in_sizes, int n_in,
                              void* d_out, int out_size, void* d_ws, size_t ws_size,
                              hipStream_t stream) {
  (void)n_in; (void)out_size; (void)ws_size;

  char* wp = (char*)d_ws;
  auto alloc = [&](size_t bytes) { char* p = wp; wp += (bytes + 255) & ~(size_t)255; return p; };

  unsigned int* dflag  = (unsigned int*)alloc(256);
  unsigned int* flags  = (unsigned int*)alloc(1024);

  CvtJobs J; J.cnt = 0; J.dflag = dflag;
  auto addcvt = [&](const void* src, int n) -> unsigned short* {
    unsigned short* p = (unsigned short*)alloc((size_t)n * 2);
    J.src[J.cnt] = src; J.dst[J.cnt] = p; J.n[J.cnt] = n; J.cnt++;
    return p;
  };
  const unsigned short* emo  = addcvt(d_in[2],  in_sizes[2]);
  const unsigned short* pw1  = addcvt(d_in[4],  in_sizes[4]);
  const unsigned short* pb1  = addcvt(d_in[5],  in_sizes[5]);
  const unsigned short* pw2  = addcvt(d_in[6],  in_sizes[6]);
  const unsigned short* pb2  = addcvt(d_in[7],  in_sizes[7]);
  const unsigned short* awih = addcvt(d_in[8],  in_sizes[8]);
  const unsigned short* awhh = addcvt(d_in[9],  in_sizes[9]);
  const unsigned short* abih = addcvt(d_in[10], in_sizes[10]);
  const unsigned short* abhh = addcvt(d_in[11], in_sizes[11]);
  const unsigned short* qw   = addcvt(d_in[12], in_sizes[12]);
  const unsigned short* cw   = addcvt(d_in[13], in_sizes[13]);
  const unsigned short* ldw  = addcvt(d_in[14], in_sizes[14]);
  const unsigned short* vw   = addcvt(d_in[15], in_sizes[15]);
  const unsigned short* vb   = addcvt(d_in[16], in_sizes[16]);
  const unsigned short* mw   = addcvt(d_in[17], in_sizes[17]);
  const unsigned short* mb   = addcvt(d_in[18], in_sizes[18]);
  const unsigned short* dwih = addcvt(d_in[19], in_sizes[19]);
  const unsigned short* dwhh = addcvt(d_in[20], in_sizes[20]);
  const unsigned short* dbih = addcvt(d_in[21], in_sizes[21]);
  const unsigned short* dbhh = addcvt(d_in[22], in_sizes[22]);
  const unsigned short* pjw  = addcvt(d_in[23], in_sizes[23]);
  const unsigned short* pjb  = addcvt(d_in[24], in_sizes[24]);
  const unsigned short* gw   = addcvt(d_in[25], in_sizes[25]);
  const unsigned short* gb   = addcvt(d_in[26], in_sizes[26]);
  const unsigned short* memb = addcvt(d_in[1],  32 * 512 * 512);

  unsigned short* xpre = (unsigned short*)alloc((size_t)800 * 32 * 256 * 2);
  float* pmemT = (float*)alloc((size_t)32 * 512 * 128 * 4);
  float* gemo = (float*)alloc((size_t)32 * 4096 * 4);
  float* qwf  = (float*)alloc((size_t)128 * 1024 * 4);
  float* ldwf = (float*)alloc((size_t)128 * 32 * 4);
  float* ahf  = (float*)alloc(32 * 1024 * 4);
  float* aw   = (float*)alloc(32 * 512 * 4);
  float* cum  = (float*)alloc(32 * 512 * 4);
  float* eng  = (float*)alloc(32 * 512 * 4);
  unsigned short* ahb  = (unsigned short*)alloc(2 * 32 * 1024 * 2);
  unsigned short* dhb  = (unsigned short*)alloc(2 * 32 * 1024 * 2);
  unsigned short* ctxb = (unsigned short*)alloc(2 * 32 * 512 * 2);

  detect_k<<<dim3(1), dim3(64), 0, stream>>>((const unsigned short*)d_in[16], dflag);
  cvt_k<<<dim3(2048), dim3(256), 0, stream>>>(J);
  qwf_k<<<dim3(512), dim3(256), 0, stream>>>(qw, qwf, ldw, ldwf);
  prenet_k<<<dim3(800), dim3(256), 0, stream>>>(d_in[0], dflag, pw1, pb1, pw2, pb2, xpre);
  gemo_k<<<dim3(512), dim3(256), 0, stream>>>(emo, awih, abih, abhh, gemo);
  pmem_k<<<dim3(1024), dim3(256), 0, stream>>>(d_in[1], dflag, mw, mb, pmemT);
  init_k<<<dim3(128), dim3(256), 0, stream>>>(ahb, dhb, ctxb, ahf, aw, cum, flags);

  Params P;
  P.memb = memb;
  P.awih = awih; P.awhh = awhh;
  P.cw = cw; P.ldw = ldw; P.vw = vw; P.vb = vb;
  P.dwih = dwih; P.dwhh = dwhh; P.dbih = dbih; P.dbhh = dbhh;
  P.pw = pjw; P.pb = pjb; P.gw = gw; P.gb = gb;
  P.pmemT = pmemT; P.gemo = gemo; P.qwf = qwf; P.ldwf = ldwf;
  P.ahf = ahf; P.aw = aw; P.cum = cum; P.eng = eng;
  P.xpre = xpre; P.ahb = ahb; P.dhb = dhb; P.ctxb = ctxb;
  P.out = d_out;
  P.flags = flags;
  P.dflag = dflag;

  static bool attr_set = false;
  if (!attr_set) {
    hipFuncSetAttribute((const void*)persist_k,
                        hipFuncAttributeMaxDynamicSharedMemorySize, DYN_LDS);
    attr_set = true;
  }
  persist_k<<<dim3(NBLK), dim3(512), DYN_LDS, stream>>>(P);
}

// Round 6
// 67733.069 us; speedup vs baseline: 1.0146x; 1.0146x over previous
//
#include <hip/hip_runtime.h>
#include <stdint.h>

// Decoder_71683004171173: persistent-kernel Tacotron decoder on gfx950.
// R6: R5 + (1) counted-vmcnt deep pipelines on all bypass A streams (16-24
// loads in flight vs 8 -> ~2x MALL throughput on the 29 MB/step activation
// broadcast); s3 K-split remapped to uniform {ah 256 | ctx 128} per wave so
// static vmcnt counts hold. (2) a1 loc stride 48->36 floats (9 units, odd ->
// conflict-free b128 reads; 48 was a 16-way conflict = the 1.87e9 counter).
// (3) a2 cr layout stride-9-per-thread (2-way max). Weights stay LDS-pinned.

typedef __attribute__((ext_vector_type(8))) short short8;
typedef __attribute__((ext_vector_type(4))) float floatx4;
typedef unsigned long long u64t;

#define NBLK 256
#define WOFF 131072
#define DYN_LDS 161408

#define MFMA(a, b, c) __builtin_amdgcn_mfma_f32_16x16x32_bf16(a, b, c, 0, 0, 0)
#define SBAR0() __builtin_amdgcn_sched_barrier(0)
#define VMWAIT(n) do { asm volatile("s_waitcnt vmcnt(" #n ")" ::: "memory"); \
                       __builtin_amdgcn_sched_barrier(0); } while (0)

__device__ __forceinline__ float b2f(unsigned short u) {
  union { unsigned int i; float f; } v; v.i = ((unsigned int)u) << 16; return v.f;
}
__device__ __forceinline__ unsigned short f2b(float f) {
  union { float f; unsigned int i; } v; v.f = f;
  unsigned int r = v.i + 0x7FFFu + ((v.i >> 16) & 1u);   // RNE
  return (unsigned short)(r >> 16);
}
__device__ __forceinline__ void stout(void* out, size_t idx, float v, int isbf) {
  if (isbf) ((unsigned short*)out)[idx] = f2b(v);
  else      ((float*)out)[idx] = v;
}
__device__ __forceinline__ float sigm(float x) {
  float xc = fminf(fmaxf(x, -30.f), 30.f);
  return 1.f / (1.f + __expf(-xc));
}
__device__ __forceinline__ float tanh_(float x) {
  float xc = fminf(fmaxf(x, -15.f), 15.f);
  float e = __expf(2.f * xc);
  return (e - 1.f) / (e + 1.f);
}
__device__ __forceinline__ float rdlane_f(float v, int l) {
  return __int_as_float(__builtin_amdgcn_readlane(__float_as_int(v), l));
}

// ---- coherent (cache-bypass) scalar accessors (relaxed agent atomics) ----
__device__ __forceinline__ float ld_f32c(const float* p) {
  union { unsigned int u; float f; } v;
  v.u = __hip_atomic_load((const unsigned int*)p, __ATOMIC_RELAXED, __HIP_MEMORY_SCOPE_AGENT);
  return v.f;
}
__device__ __forceinline__ void st_f32c(float* p, float f) {
  union { float f; unsigned int u; } v; v.f = f;
  __hip_atomic_store((unsigned int*)p, v.u, __ATOMIC_RELAXED, __HIP_MEMORY_SCOPE_AGENT);
}
__device__ __forceinline__ void st_u32c(unsigned short* p, unsigned int u) {
  __hip_atomic_store((unsigned int*)p, u, __ATOMIC_RELAXED, __HIP_MEMORY_SCOPE_AGENT);
}
__device__ __forceinline__ u64t ld_u64c(const void* p) {
  return __hip_atomic_load((const u64t*)p, __ATOMIC_RELAXED, __HIP_MEMORY_SCOPE_AGENT);
}

// ---- pipelined 16B loads via inline asm (issue now, wait explicitly) ----
__device__ __forceinline__ short8 ld16_cb(const unsigned short* p) {   // L1+L2 bypass
  short8 r;
  asm volatile("global_load_dwordx4 %0, %1, off sc0 sc1" : "=v"(r) : "v"(p));
  return r;
}
__device__ __forceinline__ short8 ld16_nc(const unsigned short* p) {   // normal cached
  short8 r;
  asm volatile("global_load_dwordx4 %0, %1, off" : "=v"(r) : "v"(p));
  return r;
}

struct Params {
  const unsigned short *memb;
  const unsigned short *awih, *awhh;
  const unsigned short *cw, *ldw, *vw, *vb;
  const unsigned short *dwih, *dwhh, *dbih, *dbhh;
  const unsigned short *pw, *pb, *gw, *gb;
  const float *pmemT, *gemo, *qwf, *ldwf;
  float *ahf, *aw, *cum, *eng;
  unsigned short *xpre;
  unsigned short *ahb, *dhb, *ctxb;
  void *out;
  unsigned int *flags;
  const unsigned int *dflag;
};

// Work-region structs (all live at lds + WOFF, time-disjoint):
struct A1W {                 // 27264 B
  float cwT0[992], cwT1[992], vvp[128];
  float awh0[96], awh1[96];
  float ahs[1056];           // [4][264]
  float pqp[512];
  float pq[128];
  float loc[64 * 36];        // stride 36 floats = 9 units (odd) -> conflict-free
  float epart[512];
};
struct A2W { float w[512]; float red[8]; float red2[8]; float cr[8 * 584]; };  // 20800 B
// gates: float[4][32][33] = 16896 B ; proj partials: float[8][32][17] = 17408 B

// ---- grid barrier: relaxed bypass store + relaxed bypass polls (R4, proven) ----
__device__ __forceinline__ void gbar(unsigned int* flags, unsigned int gen, int bid, int tid) {
  __syncthreads();
  if (tid == 0)
    __hip_atomic_store(&flags[bid], gen, __ATOMIC_RELAXED, __HIP_MEMORY_SCOPE_AGENT);
  if (tid < NBLK) {
    while (__hip_atomic_load(&flags[tid], __ATOMIC_RELAXED, __HIP_MEMORY_SCOPE_AGENT) < gen)
      __builtin_amdgcn_s_sleep(1);
  }
  __syncthreads();
}

// ---- attention LSTM step ts; block g in [0,128) owns j in [g*8, g*8+8) ----
__device__ __forceinline__ void s1_block(const Params& P, char* lds, int ts, int g, int tid, float& ac_reg) {
  const unsigned short* wih = (const unsigned short*)lds;
  const unsigned short* whh = (const unsigned short*)(lds + 49152);
  float* gt = (float*)(lds + WOFF);    // [4][32][33]
  const int w = tid >> 6, lane = tid & 63;
  const int h = w >> 2, kq = w & 3;
  const int kg = lane >> 4, nn = lane & 15, mm = lane & 15;
  const int pa = (ts + 1) & 1;
  floatx4 acc00 = {0.f,0.f,0.f,0.f}, acc01 = {0.f,0.f,0.f,0.f};
  floatx4 acc10 = {0.f,0.f,0.f,0.f}, acc11 = {0.f,0.f,0.f,0.f};
  const int sw = nn & 7;
  if (h) {   // whh over ah(ts-1), K=1024, quarter 256: 16 loads in flight
    const unsigned short* ast = P.ahb + pa * (32 * 1024);
    const int kb0 = kq * 256;
    short8 A[16];
    #pragma unroll
    for (int hf = 0; hf < 2; ++hf)
      #pragma unroll
      for (int i = 0; i < 4; ++i) {
        const int k = kb0 + hf * 128 + i * 32 + kg * 8;
        A[hf * 8 + i * 2]     = ld16_cb(ast + mm * 1024 + k);
        A[hf * 8 + i * 2 + 1] = ld16_cb(ast + (mm + 16) * 1024 + k);
      }
    SBAR0();
    VMWAIT(8);
    #pragma unroll
    for (int i = 0; i < 4; ++i) {
      const int c = ((kb0 + i * 32) >> 3) + kg;
      short8 b0 = *(const short8*)(whh + ((nn * 128 + (c ^ sw)) << 3));
      short8 b1 = *(const short8*)(whh + (((nn + 16) * 128 + (c ^ sw)) << 3));
      acc00 = MFMA(A[i*2],   b0, acc00);
      acc01 = MFMA(A[i*2],   b1, acc01);
      acc10 = MFMA(A[i*2+1], b0, acc10);
      acc11 = MFMA(A[i*2+1], b1, acc11);
    }
    VMWAIT(0);
    #pragma unroll
    for (int i = 0; i < 4; ++i) {
      const int c = ((kb0 + 128 + i * 32) >> 3) + kg;
      short8 b0 = *(const short8*)(whh + ((nn * 128 + (c ^ sw)) << 3));
      short8 b1 = *(const short8*)(whh + (((nn + 16) * 128 + (c ^ sw)) << 3));
      acc00 = MFMA(A[8+i*2],   b0, acc00);
      acc01 = MFMA(A[8+i*2],   b1, acc01);
      acc10 = MFMA(A[8+i*2+1], b0, acc10);
      acc11 = MFMA(A[8+i*2+1], b1, acc11);
    }
  } else {   // wih over [xpre 256 | ctx 512], virtual K=768, quarter 192: 12 in flight
    const unsigned short* xp = P.xpre + (size_t)ts * 32 * 256;
    const unsigned short* cx = P.ctxb + pa * (32 * 512);
    const int kb0 = kq * 192;
    short8 A[12];
    #pragma unroll
    for (int hf = 0; hf < 2; ++hf)
      #pragma unroll
      for (int i = 0; i < 3; ++i) {
        const int vk = kb0 + hf * 96 + i * 32 + kg * 8;
        if (vk < 256) {
          A[hf * 6 + i * 2]     = ld16_nc(xp + mm * 256 + vk);
          A[hf * 6 + i * 2 + 1] = ld16_nc(xp + (mm + 16) * 256 + vk);
        } else {
          A[hf * 6 + i * 2]     = ld16_cb(cx + mm * 512 + vk - 256);
          A[hf * 6 + i * 2 + 1] = ld16_cb(cx + (mm + 16) * 512 + vk - 256);
        }
      }
    SBAR0();
    VMWAIT(6);
    #pragma unroll
    for (int i = 0; i < 3; ++i) {
      const int c = ((kb0 + i * 32) >> 3) + kg;
      short8 b0 = *(const short8*)(wih + ((nn * 96 + (c ^ sw)) << 3));
      short8 b1 = *(const short8*)(wih + (((nn + 16) * 96 + (c ^ sw)) << 3));
      acc00 = MFMA(A[i*2],   b0, acc00);
      acc01 = MFMA(A[i*2],   b1, acc01);
      acc10 = MFMA(A[i*2+1], b0, acc10);
      acc11 = MFMA(A[i*2+1], b1, acc11);
    }
    VMWAIT(0);
    #pragma unroll
    for (int i = 0; i < 3; ++i) {
      const int c = ((kb0 + 96 + i * 32) >> 3) + kg;
      short8 b0 = *(const short8*)(wih + ((nn * 96 + (c ^ sw)) << 3));
      short8 b1 = *(const short8*)(wih + (((nn + 16) * 96 + (c ^ sw)) << 3));
      acc00 = MFMA(A[6+i*2],   b0, acc00);
      acc01 = MFMA(A[6+i*2],   b1, acc01);
      acc10 = MFMA(A[6+i*2+1], b0, acc10);
      acc11 = MFMA(A[6+i*2+1], b1, acc11);
    }
  }
  const int rb = kg * 4;
  if (!h) {
    #pragma unroll
    for (int v = 0; v < 4; ++v) {
      gt[(kq * 32 + rb + v) * 33 + nn]           = acc00[v];
      gt[(kq * 32 + rb + v) * 33 + nn + 16]      = acc01[v];
      gt[(kq * 32 + rb + v + 16) * 33 + nn]      = acc10[v];
      gt[(kq * 32 + rb + v + 16) * 33 + nn + 16] = acc11[v];
    }
  }
  __syncthreads();
  if (h) {
    #pragma unroll
    for (int v = 0; v < 4; ++v) {
      gt[(kq * 32 + rb + v) * 33 + nn]           += acc00[v];
      gt[(kq * 32 + rb + v) * 33 + nn + 16]      += acc01[v];
      gt[(kq * 32 + rb + v + 16) * 33 + nn]      += acc10[v];
      gt[(kq * 32 + rb + v + 16) * 33 + nn + 16] += acc11[v];
    }
  }
  __syncthreads();
  if (tid < 256) {
    const int b = tid >> 3, jl = tid & 7, j = g * 8 + jl;
    const float* gm = P.gemo + b * 4096 + j;
    float gs[4];
    #pragma unroll
    for (int c4 = 0; c4 < 4; ++c4) {
      float s = 0.f;
      #pragma unroll
      for (int q2 = 0; q2 < 4; ++q2) s += gt[(q2 * 32 + b) * 33 + c4 * 8 + jl];
      gs[c4] = s;
    }
    float gi = gs[0] + gm[0], gf = gs[1] + gm[1024], gc = gs[2] + gm[2048], go = gs[3] + gm[3072];
    float cn = sigm(gf) * ac_reg + sigm(gi) * tanh_(gc);
    float hn = sigm(go) * tanh_(cn);
    ac_reg = cn;
    st_f32c(&P.ahf[b * 1024 + j], hn);
    unsigned int hb = f2b(hn);
    unsigned int nb = (unsigned int)__shfl_down((int)hb, 1) & 0xFFFFu;
    if (!(jl & 1))
      st_u32c(P.ahb + (ts & 1) * (32 * 1024) + b * 1024 + j, hb | (nb << 16));
  }
}

// ---- decoder LSTM step ts; block g in [0,128) owns j in [g*8, g*8+8) ----
// wave kq covers ah cols [kq*256,+256) and ctx cols [kq*128,+128) (uniform shape).
__device__ __forceinline__ void s3_block(const Params& P, char* lds, int ts, int g, int tid, float& dc_reg) {
  const unsigned short* wia = (const unsigned short*)lds;
  const unsigned short* whh = (const unsigned short*)(lds + 65536);
  float* gt = (float*)(lds + WOFF);
  const int w = tid >> 6, lane = tid & 63;
  const int h = w >> 2, kq = w & 3;
  const int kg = lane >> 4, nn = lane & 15, mm = lane & 15;
  const int pa = ts & 1, pd = (ts + 1) & 1;
  floatx4 acc00 = {0.f,0.f,0.f,0.f}, acc01 = {0.f,0.f,0.f,0.f};
  floatx4 acc10 = {0.f,0.f,0.f,0.f}, acc11 = {0.f,0.f,0.f,0.f};
  const int sw = nn & 7;
  if (h) {   // dwhh over dh(ts-1), K=1024: 16 loads in flight
    const unsigned short* ast = P.dhb + pd * (32 * 1024);
    const int kb0 = kq * 256;
    short8 A[16];
    #pragma unroll
    for (int hf = 0; hf < 2; ++hf)
      #pragma unroll
      for (int i = 0; i < 4; ++i) {
        const int k = kb0 + hf * 128 + i * 32 + kg * 8;
        A[hf * 8 + i * 2]     = ld16_cb(ast + mm * 1024 + k);
        A[hf * 8 + i * 2 + 1] = ld16_cb(ast + (mm + 16) * 1024 + k);
      }
    SBAR0();
    VMWAIT(8);
    #pragma unroll
    for (int i = 0; i < 4; ++i) {
      const int c = ((kb0 + i * 32) >> 3) + kg;
      short8 b0 = *(const short8*)(whh + ((nn * 128 + (c ^ sw)) << 3));
      short8 b1 = *(const short8*)(whh + (((nn + 16) * 128 + (c ^ sw)) << 3));
      acc00 = MFMA(A[i*2],   b0, acc00);
      acc01 = MFMA(A[i*2],   b1, acc01);
      acc10 = MFMA(A[i*2+1], b0, acc10);
      acc11 = MFMA(A[i*2+1], b1, acc11);
    }
    VMWAIT(0);
    #pragma unroll
    for (int i = 0; i < 4; ++i) {
      const int c = ((kb0 + 128 + i * 32) >> 3) + kg;
      short8 b0 = *(const short8*)(whh + ((nn * 128 + (c ^ sw)) << 3));
      short8 b1 = *(const short8*)(whh + (((nn + 16) * 128 + (c ^ sw)) << 3));
      acc00 = MFMA(A[8+i*2],   b0, acc00);
      acc01 = MFMA(A[8+i*2],   b1, acc01);
      acc10 = MFMA(A[8+i*2+1], b0, acc10);
      acc11 = MFMA(A[8+i*2+1], b1, acc11);
    }
  } else {   // dwih: ah quarter (2 batches x 8) then ctx eighth (16 incl. B)
    const unsigned short* ah = P.ahb + pa * (32 * 1024);
    const unsigned short* cx = P.ctxb + pa * (32 * 512);
    const int rz0 = (nn >> 3) * 1024 + g * 8 + (nn & 7);
    short8 Aa[16], Ac[16];
    #pragma unroll
    for (int i = 0; i < 4; ++i) {        // batch0: ah [kq*256, +128)
      const int k = kq * 256 + i * 32 + kg * 8;
      Aa[i * 2]     = ld16_cb(ah + mm * 1024 + k);
      Aa[i * 2 + 1] = ld16_cb(ah + (mm + 16) * 1024 + k);
    }
    #pragma unroll
    for (int i = 0; i < 4; ++i) {        // batch1: ah [kq*256+128, +128)
      const int k = kq * 256 + 128 + i * 32 + kg * 8;
      Aa[8 + i * 2]     = ld16_cb(ah + mm * 1024 + k);
      Aa[8 + i * 2 + 1] = ld16_cb(ah + (mm + 16) * 1024 + k);
    }
    SBAR0();
    VMWAIT(8);
    #pragma unroll
    for (int i = 0; i < 4; ++i) {        // mfma batch0
      const int c = kq * 32 + i * 4 + kg;
      short8 b0 = *(const short8*)(wia + ((nn * 128 + (c ^ sw)) << 3));
      short8 b1 = *(const short8*)(wia + (((nn + 16) * 128 + (c ^ sw)) << 3));
      acc00 = MFMA(Aa[i*2],   b0, acc00);
      acc01 = MFMA(Aa[i*2],   b1, acc01);
      acc10 = MFMA(Aa[i*2+1], b0, acc10);
      acc11 = MFMA(Aa[i*2+1], b1, acc11);
    }
    SBAR0();
    #pragma unroll
    for (int i = 0; i < 4; ++i) {        // batch2: ctx [kq*128, +128), A + global B
      const int kc = kq * 128 + i * 32 + kg * 8;
      Ac[i * 4 + 0] = ld16_cb(cx + mm * 512 + kc);
      Ac[i * 4 + 1] = ld16_cb(cx + (mm + 16) * 512 + kc);
      Ac[i * 4 + 2] = ld16_nc(P.dwih + (size_t)rz0 * 1536 + 1024 + kc);
      Ac[i * 4 + 3] = ld16_nc(P.dwih + (size_t)(rz0 + 2048) * 1536 + 1024 + kc);
    }
    SBAR0();
    VMWAIT(16);
    #pragma unroll
    for (int i = 0; i < 4; ++i) {        // mfma batch1
      const int c = kq * 32 + 16 + i * 4 + kg;
      short8 b0 = *(const short8*)(wia + ((nn * 128 + (c ^ sw)) << 3));
      short8 b1 = *(const short8*)(wia + (((nn + 16) * 128 + (c ^ sw)) << 3));
      acc00 = MFMA(Aa[8+i*2],   b0, acc00);
      acc01 = MFMA(Aa[8+i*2],   b1, acc01);
      acc10 = MFMA(Aa[8+i*2+1], b0, acc10);
      acc11 = MFMA(Aa[8+i*2+1], b1, acc11);
    }
    VMWAIT(0);
    #pragma unroll
    for (int i = 0; i < 4; ++i) {        // mfma batch2
      acc00 = MFMA(Ac[i*4+0], Ac[i*4+2], acc00);
      acc01 = MFMA(Ac[i*4+0], Ac[i*4+3], acc01);
      acc10 = MFMA(Ac[i*4+1], Ac[i*4+2], acc10);
      acc11 = MFMA(Ac[i*4+1], Ac[i*4+3], acc11);
    }
  }
  const int rb = kg * 4;
  if (!h) {
    #pragma unroll
    for (int v = 0; v < 4; ++v) {
      gt[(kq * 32 + rb + v) * 33 + nn]           = acc00[v];
      gt[(kq * 32 + rb + v) * 33 + nn + 16]      = acc01[v];
      gt[(kq * 32 + rb + v + 16) * 33 + nn]      = acc10[v];
      gt[(kq * 32 + rb + v + 16) * 33 + nn + 16] = acc11[v];
    }
  }
  __syncthreads();
  if (h) {
    #pragma unroll
    for (int v = 0; v < 4; ++v) {
      gt[(kq * 32 + rb + v) * 33 + nn]           += acc00[v];
      gt[(kq * 32 + rb + v) * 33 + nn + 16]      += acc01[v];
      gt[(kq * 32 + rb + v + 16) * 33 + nn]      += acc10[v];
      gt[(kq * 32 + rb + v + 16) * 33 + nn + 16] += acc11[v];
    }
  }
  __syncthreads();
  if (tid < 256) {
    const int b = tid >> 3, jl = tid & 7, j = g * 8 + jl;
    float gs[4];
    #pragma unroll
    for (int c4 = 0; c4 < 4; ++c4) {
      float s = 0.f;
      #pragma unroll
      for (int q2 = 0; q2 < 4; ++q2) s += gt[(q2 * 32 + b) * 33 + c4 * 8 + jl];
      gs[c4] = s;
    }
    float gi = gs[0] + b2f(P.dbih[j])        + b2f(P.dbhh[j]);
    float gf = gs[1] + b2f(P.dbih[1024 + j]) + b2f(P.dbhh[1024 + j]);
    float gc = gs[2] + b2f(P.dbih[2048 + j]) + b2f(P.dbhh[2048 + j]);
    float go = gs[3] + b2f(P.dbih[3072 + j]) + b2f(P.dbhh[3072 + j]);
    float cn = sigm(gf) * dc_reg + sigm(gi) * tanh_(gc);
    float hn = sigm(go) * tanh_(cn);
    dc_reg = cn;
    unsigned int hb = f2b(hn);
    unsigned int nb = (unsigned int)__shfl_down((int)hb, 1) & 0xFFFFu;
    if (!(jl & 1))
      st_u32c(P.dhb + (ts & 1) * (32 * 1024) + b * 1024 + j, hb | (nb << 16));
  }
}

// ---- mel + gate projection for step tp; blocks 128..133 (p=0..5), 16 rows each ----
__device__ __forceinline__ void proj_block(const Params& P, char* lds, int tp, int p, int tid) {
  float* pp = (float*)(lds + WOFF);   // [8][32][17]
  const int w = tid >> 6, lane = tid & 63;
  const int kg = lane >> 4, nn = lane & 15, mm = lane & 15;
  const int pd = tp & 1;
  const int r0 = p * 16 + nn;
  const unsigned short* brow = (r0 < 80) ? (P.pw + (size_t)r0 * 1536) : P.gw;
  const unsigned short* dh = P.dhb + pd * (32 * 1024);
  const unsigned short* cx = P.ctxb + pd * (32 * 512);
  floatx4 acc0 = {0.f,0.f,0.f,0.f}, acc1 = {0.f,0.f,0.f,0.f};
  const int kb0 = w * 192;
  short8 A[18];
  #pragma unroll
  for (int bt = 0; bt < 2; ++bt)
    #pragma unroll
    for (int i = 0; i < 3; ++i) {
      const int vk = kb0 + bt * 96 + i * 32 + kg * 8;
      const int idx = bt * 9 + i * 3;
      if (vk < 1024) {
        A[idx]     = ld16_cb(dh + mm * 1024 + vk);
        A[idx + 1] = ld16_cb(dh + (mm + 16) * 1024 + vk);
      } else {
        A[idx]     = ld16_cb(cx + mm * 512 + vk - 1024);
        A[idx + 1] = ld16_cb(cx + (mm + 16) * 512 + vk - 1024);
      }
      A[idx + 2] = ld16_nc(brow + vk);
    }
  SBAR0();
  VMWAIT(9);
  #pragma unroll
  for (int i = 0; i < 3; ++i) {
    acc0 = MFMA(A[i*3],     A[i*3+2], acc0);
    acc1 = MFMA(A[i*3+1],   A[i*3+2], acc1);
  }
  VMWAIT(0);
  #pragma unroll
  for (int i = 0; i < 3; ++i) {
    acc0 = MFMA(A[9+i*3],   A[9+i*3+2], acc0);
    acc1 = MFMA(A[9+i*3+1], A[9+i*3+2], acc1);
  }
  const int rb = kg * 4;
  #pragma unroll
  for (int v = 0; v < 4; ++v) {
    pp[(w * 32 + rb + v) * 17 + nn]      = acc0[v];
    pp[(w * 32 + rb + v + 16) * 17 + nn] = acc1[v];
  }
  __syncthreads();
  {
    const int isbf = (int)*P.dflag;
    const int b = tid >> 4, nl = tid & 15, r = p * 16 + nl;
    if (r <= 80) {
      float s = 0.f;
      #pragma unroll
      for (int q2 = 0; q2 < 8; ++q2) s += pp[(q2 * 32 + b) * 17 + nl];
      if (r < 80) {
        s += b2f(P.pb[r]);
        stout(P.out, ((size_t)b * 80 + r) * 800 + tp, s, isbf);
      } else {
        s += b2f(P.gb[0]);
        stout(P.out, 2048000u + (size_t)b * 800 + tp, s, isbf);
      }
    }
  }
}

// ---- energies for step t: all 256 blocks; block = (b = bid>>3, 64-wide chunk) ----
__device__ __forceinline__ void a1_block(const Params& P, char* lds, const float* ldwR,
                                         int t, int bid, int tid) {
  A1W& q = *(A1W*)(lds + WOFF);
  const int b = bid >> 3, T0 = (bid & 7) * 64;
  for (int i = tid; i < 992; i += 512) {
    const int k = i >> 5, f = i & 31;
    q.cwT0[i] = b2f(P.cw[f * 62 + k]);
    q.cwT1[i] = b2f(P.cw[f * 62 + 31 + k]);
  }
  {
    union { u64t qq; float f[2]; } u;
    u.qq = ld_u64c(P.ahf + b * 1024 + tid * 2);
    const int v = tid * 2, qq = v >> 8, k = v & 255;
    q.ahs[qq * 264 + k]     = u.f[0];
    q.ahs[qq * 264 + k + 1] = u.f[1];
  }
  if (tid < 96) {
    const int gidx = T0 - 15 + tid;
    q.awh0[tid] = (tid < 94 && gidx >= 0 && gidx < 512) ? ld_f32c(P.aw + b * 512 + gidx) : 0.f;
  } else if (tid >= 128 && tid < 224) {
    const int i = tid - 128, gidx = T0 - 15 + i;
    q.awh1[i] = (i < 94 && gidx >= 0 && gidx < 512) ? ld_f32c(P.cum + b * 512 + gidx) : 0.f;
  } else if (tid >= 256 && tid < 384) {
    q.vvp[tid - 256] = b2f(P.vw[tid - 256]);
  }
  __syncthreads();
  { // pq partials: thread = (a, quarter-of-K)
    const int a = tid >> 2, qq = tid & 3;
    const float* qr = P.qwf + (size_t)a * 1024 + qq * 256;
    const float* al = &q.ahs[qq * 264];
    float s = 0.f;
    #pragma unroll 8
    for (int k = 0; k < 256; k += 4) {
      floatx4 w4 = *(const floatx4*)(qr + k);
      floatx4 a4 = *(const floatx4*)(al + k);
      s += w4[0]*a4[0] + w4[1]*a4[1] + w4[2]*a4[2] + w4[3]*a4[3];
    }
    q.pqp[tid] = s;
  }
  { // location conv: thread = (f, quad of 4 contiguous tl); windows in registers
    const int f = tid & 31, tl0 = (tid >> 5) * 4;
    float a4[4] = {0.f,0.f,0.f,0.f};
    #pragma unroll
    for (int kb = 0; kb < 4; ++kb) {
      const int kbase = kb * 8;
      floatx4 W0[3], W1[3];
      #pragma unroll
      for (int x = 0; x < 3; ++x) {
        W0[x] = *(const floatx4*)&q.awh0[tl0 + kbase + x * 4];
        W1[x] = *(const floatx4*)&q.awh1[tl0 + kbase + x * 4];
      }
      #pragma unroll
      for (int kk = 0; kk < 8; ++kk) {
        if (kbase + kk > 30) break;
        const float c0 = q.cwT0[(kbase + kk) * 32 + f];
        const float c1 = q.cwT1[(kbase + kk) * 32 + f];
        #pragma unroll
        for (int i = 0; i < 4; ++i) {
          const int x = kk + i;
          a4[i] += W0[x >> 2][x & 3] * c0 + W1[x >> 2][x & 3] * c1;
        }
      }
    }
    #pragma unroll
    for (int i = 0; i < 4; ++i) q.loc[(tl0 + i) * 36 + f] = a4[i];
  }
  __syncthreads();
  if (tid < 128) {
    const float* pp = &q.pqp[tid * 4];
    q.pq[tid] = pp[0] + pp[1] + pp[2] + pp[3];
  }
  __syncthreads();
  { // energies: wave aq owns 16 a; lane = tl; ldw via readlane (0 LDS)
    const int aq = tid >> 6, tl = tid & 63;
    floatx4 lr[8];
    #pragma unroll
    for (int j = 0; j < 8; ++j) lr[j] = *(const floatx4*)&q.loc[tl * 36 + j * 4];
    const float* pmr = P.pmemT + ((size_t)b * 128 + aq * 16) * 512 + T0 + tl;
    float part = 0.f;
    #pragma unroll
    for (int ii = 0; ii < 16; ++ii) {
      const int a = aq * 16 + ii;
      float s = q.pq[a] + pmr[(size_t)ii * 512];
      #pragma unroll
      for (int cc = 0; cc < 4; ++cc) {
        #pragma unroll
        for (int j = 0; j < 8; ++j) {
          const float wv_ = rdlane_f(ldwR[j], ii * 4 + cc);
          const int f = cc * 8 + j;
          s += lr[f >> 2][f & 3] * wv_;
        }
      }
      part += q.vvp[a] * tanh_(s);
    }
    q.epart[aq * 64 + tl] = part;
  }
  __syncthreads();
  if (tid < 64) {
    float e = b2f(P.vb[0]);
    #pragma unroll
    for (int j = 0; j < 8; ++j) e += q.epart[j * 64 + tid];
    st_f32c(P.eng + b * 512 + T0 + tid, e);
  }
}

// ---- softmax + context for step t: blocks 0..31 ----
__device__ __forceinline__ void a2_block(const Params& P, char* lds, int t, int b, int tid, float& cum_reg) {
  A2W& s2 = *(A2W*)(lds + WOFF);
  const int lane = tid & 63, wv = tid >> 6;
  const int isbf = (int)*P.dflag;
  float e = ld_f32c(P.eng + b * 512 + tid);
  float m = e;
  #pragma unroll
  for (int off = 32; off; off >>= 1) m = fmaxf(m, __shfl_xor(m, off));
  if (lane == 0) s2.red[wv] = m;
  __syncthreads();
  float M = s2.red[0];
  #pragma unroll
  for (int i = 1; i < 8; ++i) M = fmaxf(M, s2.red[i]);
  float p = __expf(e - M);
  float s = p;
  #pragma unroll
  for (int off = 32; off; off >>= 1) s += __shfl_xor(s, off);
  if (lane == 0) s2.red2[wv] = s;
  __syncthreads();
  float S = s2.red2[0];
  #pragma unroll
  for (int i = 1; i < 8; ++i) S += s2.red2[i];
  float wgt = p / S * (1.f / (1.f + 1e-8f));
  st_f32c(P.aw + b * 512 + tid, wgt);
  cum_reg += wgt;
  st_f32c(P.cum + b * 512 + tid, cum_reg);
  stout(P.out, 2073600u + ((size_t)b * 800 + t) * 512 + tid, wgt, isbf);
  s2.w[tid] = wgt;
  __syncthreads();
  {
    const int eg = tid & 63, tc = tid >> 6;
    const unsigned short* mp = P.memb + (size_t)b * 262144 + (size_t)tc * 64 * 512 + eg * 8;
    float acc[8] = {0.f,0.f,0.f,0.f,0.f,0.f,0.f,0.f};
    #pragma unroll 8
    for (int tau = 0; tau < 64; ++tau) {
      short8 mv = *(const short8*)(mp + (size_t)tau * 512);
      float wv_ = s2.w[tc * 64 + tau];
      #pragma unroll
      for (int j = 0; j < 8; ++j) acc[j] += wv_ * b2f((unsigned short)mv[j]);
    }
    #pragma unroll
    for (int j = 0; j < 8; ++j) s2.cr[tc * 584 + eg * 9 + j] = acc[j];   // 9-stride: 2-way max
  }
  __syncthreads();
  {
    float cx = 0.f;
    #pragma unroll
    for (int j = 0; j < 8; ++j) cx += s2.cr[j * 584 + (tid >> 3) * 9 + (tid & 7)];
    unsigned int cb = f2b(cx);
    unsigned int nb = (unsigned int)__shfl_down((int)cb, 1) & 0xFFFFu;
    if (!(tid & 1))
      st_u32c(P.ctxb + (t & 1) * (32 * 512) + b * 512 + tid, cb | (nb << 16));
  }
}

__global__ __launch_bounds__(512, 2) void persist_k(Params P) {
  extern __shared__ char lds[];
  const int tid = threadIdx.x, bid = blockIdx.x;
  // ---- persistent weight fill (once) ----
  if (bid < 128) {
    const int g = bid;
    unsigned short* wih = (unsigned short*)lds;
    unsigned short* whh = (unsigned short*)(lds + 49152);
    for (int u = tid; u < 32 * 96; u += 512) {
      const int n = u / 96, c = u % 96;
      const int row = (n >> 3) * 1024 + g * 8 + (n & 7);
      *(short8*)(wih + ((n * 96 + (c ^ (n & 7))) << 3)) =
          *(const short8*)(P.awih + (size_t)row * 1024 + c * 8);
    }
    for (int u = tid; u < 32 * 128; u += 512) {
      const int n = u >> 7, c = u & 127;
      const int row = (n >> 3) * 1024 + g * 8 + (n & 7);
      *(short8*)(whh + ((n * 128 + (c ^ (n & 7))) << 3)) =
          *(const short8*)(P.awhh + (size_t)row * 1024 + c * 8);
    }
  } else {
    const int g = bid - 128;
    unsigned short* wia = (unsigned short*)lds;
    unsigned short* whh = (unsigned short*)(lds + 65536);
    for (int u = tid; u < 32 * 128; u += 512) {
      const int n = u >> 7, c = u & 127;
      const int row = (n >> 3) * 1024 + g * 8 + (n & 7);
      *(short8*)(wia + ((n * 128 + (c ^ (n & 7))) << 3)) =
          *(const short8*)(P.dwih + (size_t)row * 1536 + c * 8);
      *(short8*)(whh + ((n * 128 + (c ^ (n & 7))) << 3)) =
          *(const short8*)(P.dwhh + (size_t)row * 1024 + c * 8);
    }
  }
  float ldwR[8];
  {
    const int a = (tid >> 6) * 16 + ((tid & 63) >> 2);
    const int cc = tid & 3;
    #pragma unroll
    for (int j = 0; j < 8; ++j) ldwR[j] = P.ldwf[a * 32 + cc * 8 + j];
  }
  __syncthreads();
  float ac_reg = 0.f, dc_reg = 0.f, cum_reg = 0.f;
  unsigned int gen = 0;
  if (bid < 128) s1_block(P, lds, 0, bid, tid, ac_reg);
  gbar(P.flags, ++gen, bid, tid);
  for (int t = 0; t < 800; ++t) {
    a1_block(P, lds, ldwR, t, bid, tid);
    gbar(P.flags, ++gen, bid, tid);
    if (bid < 32) a2_block(P, lds, t, bid, tid, cum_reg);
    else if (bid >= 128 && t >= 1) s3_block(P, lds, t - 1, bid - 128, tid, dc_reg);
    gbar(P.flags, ++gen, bid, tid);
    if (bid < 128) { if (t < 799) s1_block(P, lds, t + 1, bid, tid, ac_reg); }
    else if (bid < 134 && t >= 1) proj_block(P, lds, t - 1, bid - 128, tid);
    gbar(P.flags, ++gen, bid, tid);
  }
  if (bid >= 128) s3_block(P, lds, 799, bid - 128, tid, dc_reg);
  gbar(P.flags, ++gen, bid, tid);
  if (bid >= 128 && bid < 134) proj_block(P, lds, 799, bid - 128, tid);
}

// ---------------- dtype detect + canonicalize ----------------
__global__ void detect_k(const unsigned short* vb_raw, unsigned int* dflag) {
  if (threadIdx.x == 0 && blockIdx.x == 0)
    *dflag = (vb_raw[0] == 0xBF80u) ? 1u : 0u;
}

struct CvtJobs {
  const void* src[28];
  unsigned short* dst[28];
  int n[28];
  int cnt;
  const unsigned int* dflag;
};

__global__ void cvt_k(CvtJobs J) {
  const int isbf = (int)*J.dflag;
  const int gid = blockIdx.x * 256 + threadIdx.x, stride = gridDim.x * 256;
  for (int tj = 0; tj < J.cnt; ++tj) {
    const int n = J.n[tj];
    unsigned short* d = J.dst[tj];
    if (isbf) {
      const unsigned short* s = (const unsigned short*)J.src[tj];
      for (int i = gid; i < n; i += stride) d[i] = s[i];
    } else {
      const float* s = (const float*)J.src[tj];
      for (int i = gid; i < n; i += stride) d[i] = f2b(s[i]);
    }
  }
}

__global__ void qwf_k(const unsigned short* qw, float* qwf,
                      const unsigned short* ldw, float* ldwf) {
  const int i = blockIdx.x * 256 + threadIdx.x;   // 131072 = 128 x 1024
  qwf[i] = b2f(qw[i]);
  if (i < 4096) ldwf[i] = b2f(ldw[i]);
}

// ---------------- precompute kernels ----------------
__global__ void prenet_k(const void* dec, const unsigned int* dflag,
                         const unsigned short* w1, const unsigned short* b1,
                         const unsigned short* w2, const unsigned short* b2, unsigned short* xpre) {
  const int t = blockIdx.x, tid = threadIdx.x;
  const int isbf = (int)*dflag;
  __shared__ float sin_[32 * 80];
  __shared__ float h1[32 * 256];
  for (int i = tid; i < 2560; i += 256) {
    int b = i / 80, m = i % 80;
    size_t idx = ((size_t)b * 80 + m) * 800 + t - 1;
    float v;
    if (t == 0) v = -4.5f;
    else if (isbf) v = b2f(((const unsigned short*)dec)[idx]);
    else v = ((const float*)dec)[idx];
    sin_[i] = v;
  }
  __syncthreads();
  for (int u = tid; u < 8192; u += 256) {
    int b = u >> 8, o = u & 255;
    float s = b2f(b1[o]);
    const unsigned short* wr = w1 + o * 80;
    const float* sr = &sin_[b * 80];
    for (int k = 0; k < 80; ++k) s += b2f(wr[k]) * sr[k];
    h1[u] = fmaxf(s, 0.f);
  }
  __syncthreads();
  for (int u = tid; u < 8192; u += 256) {
    int b = u >> 8, o = u & 255;
    float s = b2f(b2[o]);
    const unsigned short* wr = w2 + o * 256;
    const float* hr = &h1[b * 256];
    for (int k = 0; k < 256; ++k) s += b2f(wr[k]) * hr[k];
    xpre[(size_t)(t * 32 + b) * 256 + o] = f2b(fmaxf(s, 0.f));
  }
}

__global__ void gemo_k(const unsigned short* emo, const unsigned short* wih,
                       const unsigned short* bih, const unsigned short* bhh, float* gemo) {
  const int gid = blockIdx.x * 256 + threadIdx.x;
  const int r = gid >> 5, b = gid & 31;
  float s = b2f(bih[r]) + b2f(bhh[r]);
  const unsigned short* wr = wih + (size_t)r * 1024 + 768;
  const unsigned short* er = emo + b * 256;
  for (int k = 0; k < 256; ++k) s += b2f(er[k]) * b2f(wr[k]);
  gemo[b * 4096 + r] = s;
}

__global__ void pmem_k(const void* mem, const unsigned int* dflag, const unsigned short* mw,
                       const unsigned short* mb, float* pmemT) {
  const int b = blockIdx.x >> 5, tq = blockIdx.x & 31, tid = threadIdx.x;
  const int isbf = (int)*dflag;
  __shared__ float mt[16 * 512];
  for (int i = tid; i < 8192; i += 256) {
    size_t idx = (size_t)(b * 512 + tq * 16) * 512 + i;
    mt[i] = isbf ? b2f(((const unsigned short*)mem)[idx]) : ((const float*)mem)[idx];
  }
  __syncthreads();
  for (int u = tid; u < 2048; u += 256) {
    int tl = u >> 7, a = u & 127;
    float s = b2f(mb[a]);
    const unsigned short* wr = mw + a * 512;
    const float* mr = &mt[tl * 512];
    for (int k = 0; k < 512; ++k) s += b2f(wr[k]) * mr[k];
    pmemT[((size_t)b * 128 + a) * 512 + tq * 16 + tl] = s;   // [b][a][t]
  }
}

__global__ void init_k(unsigned short* ahb, unsigned short* dhb, unsigned short* ctxb,
                       float* ahf, float* aw, float* cum, unsigned int* flags) {
  const int gid = blockIdx.x * 256 + threadIdx.x;
  const int n = gridDim.x * 256;
  for (int i = gid; i < 65536; i += n) { ahb[i] = 0; dhb[i] = 0; }
  for (int i = gid; i < 32768; i += n) { ctxb[i] = 0; ahf[i] = 0.f; }
  for (int i = gid; i < 16384; i += n) {
    int tt = i & 511;
    aw[i] = (tt < 5) ? 0.2f : 0.f;
    cum[i] = 0.f;
  }
  for (int i = gid; i < 256; i += n) flags[i] = 0;
}

extern "C" void kernel_launch(void* const* d_in, const int* in_sizes, int n_in,
                              void* d_out, int out_size, void* d_ws, size_t ws_size,
                              hipStream_t stream) {
  (void)n_in; (void)out_size; (void)ws_size;

  char* wp = (char*)d_ws;
  auto alloc = [&](size_t bytes) { char* p = wp; wp += (bytes + 255) & ~(size_t)255; return p; };

  unsigned int* dflag  = (unsigned int*)alloc(256);
  unsigned int* flags  = (unsigned int*)alloc(1024);

  CvtJobs J; J.cnt = 0; J.dflag = dflag;
  auto addcvt = [&](const void* src, int n) -> unsigned short* {
    unsigned short* p = (unsigned short*)alloc((size_t)n * 2);
    J.src[J.cnt] = src; J.dst[J.cnt] = p; J.n[J.cnt] = n; J.cnt++;
    return p;
  };
  const unsigned short* emo  = addcvt(d_in[2],  in_sizes[2]);
  const unsigned short* pw1  = addcvt(d_in[4],  in_sizes[4]);
  const unsigned short* pb1  = addcvt(d_in[5],  in_sizes[5]);
  const unsigned short* pw2  = addcvt(d_in[6],  in_sizes[6]);
  const unsigned short* pb2  = addcvt(d_in[7],  in_sizes[7]);
  const unsigned short* awih = addcvt(d_in[8],  in_sizes[8]);
  const unsigned short* awhh = addcvt(d_in[9],  in_sizes[9]);
  const unsigned short* abih = addcvt(d_in[10], in_sizes[10]);
  const unsigned short* abhh = addcvt(d_in[11], in_sizes[11]);
  const unsigned short* qw   = addcvt(d_in[12], in_sizes[12]);
  const unsigned short* cw   = addcvt(d_in[13], in_sizes[13]);
  const unsigned short* ldw  = addcvt(d_in[14], in_sizes[14]);
  const unsigned short* vw   = addcvt(d_in[15], in_sizes[15]);
  const unsigned short* vb   = addcvt(d_in[16], in_sizes[16]);
  const unsigned short* mw   = addcvt(d_in[17], in_sizes[17]);
  const unsigned short* mb   = addcvt(d_in[18], in_sizes[18]);
  const unsigned short* dwih = addcvt(d_in[19], in_sizes[19]);
  const unsigned short* dwhh = addcvt(d_in[20], in_sizes[20]);
  const unsigned short* dbih = addcvt(d_in[21], in_sizes[21]);
  const unsigned short* dbhh = addcvt(d_in[22], in_sizes[22]);
  const unsigned short* pjw  = addcvt(d_in[23], in_sizes[23]);
  const unsigned short* pjb  = addcvt(d_in[24], in_sizes[24]);
  const unsigned short* gw   = addcvt(d_in[25], in_sizes[25]);
  const unsigned short* gb   = addcvt(d_in[26], in_sizes[26]);
  const unsigned short* memb = addcvt(d_in[1],  32 * 512 * 512);

  unsigned short* xpre = (unsigned short*)alloc((size_t)800 * 32 * 256 * 2);
  float* pmemT = (float*)alloc((size_t)32 * 512 * 128 * 4);
  float* gemo = (float*)alloc((size_t)32 * 4096 * 4);
  float* qwf  = (float*)alloc((size_t)128 * 1024 * 4);
  float* ldwf = (float*)alloc((size_t)128 * 32 * 4);
  float* ahf  = (float*)alloc(32 * 1024 * 4);
  float* aw   = (float*)alloc(32 * 512 * 4);
  float* cum  = (float*)alloc(32 * 512 * 4);
  float* eng  = (float*)alloc(32 * 512 * 4);
  unsigned short* ahb  = (unsigned short*)alloc(2 * 32 * 1024 * 2);
  unsigned short* dhb  = (unsigned short*)alloc(2 * 32 * 1024 * 2);
  unsigned short* ctxb = (unsigned short*)alloc(2 * 32 * 512 * 2);

  detect_k<<<dim3(1), dim3(64), 0, stream>>>((const unsigned short*)d_in[16], dflag);
  cvt_k<<<dim3(2048), dim3(256), 0, stream>>>(J);
  qwf_k<<<dim3(512), dim3(256), 0, stream>>>(qw, qwf, ldw, ldwf);
  prenet_k<<<dim3(800), dim3(256), 0, stream>>>(d_in[0], dflag, pw1, pb1, pw2, pb2, xpre);
  gemo_k<<<dim3(512), dim3(256), 0, stream>>>(emo, awih, abih, abhh, gemo);
  pmem_k<<<dim3(1024), dim3(256), 0, stream>>>(d_in[1], dflag, mw, mb, pmemT);
  init_k<<<dim3(128), dim3(256), 0, stream>>>(ahb, dhb, ctxb, ahf, aw, cum, flags);

  Params P;
  P.memb = memb;
  P.awih = awih; P.awhh = awhh;
  P.cw = cw; P.ldw = ldw; P.vw = vw; P.vb = vb;
  P.dwih = dwih; P.dwhh = dwhh; P.dbih = dbih; P.dbhh = dbhh;
  P.pw = pjw; P.pb = pjb; P.gw = gw; P.gb = gb;
  P.pmemT = pmemT; P.gemo = gemo; P.qwf = qwf; P.ldwf = ldwf;
  P.ahf = ahf; P.aw = aw; P.cum = cum; P.eng = eng;
  P.xpre = xpre; P.ahb = ahb; P.dhb = dhb; P.ctxb = ctxb;
  P.out = d_out;
  P.flags = flags;
  P.dflag = dflag;

  static bool attr_set = false;
  if (!attr_set) {
    hipFuncSetAttribute((const void*)persist_k,
                        hipFuncAttributeMaxDynamicSharedMemorySize, DYN_LDS);
    attr_set = true;
  }
  persist_k<<<dim3(NBLK), dim3(512), DYN_LDS, stream>>>(P);
}